// Round 11
// baseline (1041.445 us; speedup 1.0000x reference)
//
#include <hip/hip_runtime.h>
#include <cmath>
#include <cstdint>
#include <cstddef>

// LIF network. Facts exploited:
//  (1) s==0 forever -> recurrent term dead (recurrent_weights, E/I_weight unused).
//  (2) ff = X @ Wff^T is a GEMM; X is exactly 0/1 -> exact in f16. Weights
//      split f16 hi/lo with x1024 scaling (residual <= 2^-22 rel). K = 2048.
//  (3) per T-chunk kernel: ff(chunk c) via MFMA + recurrence(chunk c-1) +
//      xconv(chunk c+1), one segment per block range, grid = 256 = CU count.
//  R10 post-mortem: R8/R9/R10 all restructured the LDS<->MFMA sync and all
//      regressed vs the 72us R6/R7 structure -> that family is at its ceiling.
//      This version DELETES the LDS: MFMA fragments are 16 contiguous bytes
//      of global memory (row*stride + kh*16), loaded directly to VGPRs.
//      B panels XCD-pinned in L2 (2MB), X16 chunk L2-resident; 4x A / 2x B
//      cross-wave redundancy absorbed by L1. Zero barriers, zero waitcnts:
//      compiler schedules freely; 2 waves/SIMD TLP hides latency.
//      Same kq-ascending accumulate order -> bitwise-identical output.
//
// ws layout: [ Wt2 (N x 2*NI) f16 | X16 (B*T x NI) f16 |
//              state 2*B*N f32 | ffA | ffB (TC*B*N f32 each) ]

typedef _Float16 half8 __attribute__((ext_vector_type(8)));
typedef float floatx4 __attribute__((ext_vector_type(4)));

#define WSCALE 1024.0f
#define WSCALE_INV (1.0f / 1024.0f)

// ---- W prep: Wt2[n][k] f16, k<NI: hi(1024*Wff[n][k]); k>=NI: lo residual ----
__global__ __launch_bounds__(256) void k_wprep(const float* __restrict__ Wff,
                                               _Float16* __restrict__ Wt2,
                                               int N, int NI) {
    int tid = blockIdx.x * 256 + (int)threadIdx.x;
    int per_row = NI >> 3;
    int n = tid / per_row;
    int ic = (tid - n * per_row) << 3;
    if (n >= N) return;
    const float4* src = (const float4*)(Wff + (size_t)n * NI + ic);
    float4 w0 = src[0], w1 = src[1];
    float wv[8] = {w0.x, w0.y, w0.z, w0.w, w1.x, w1.y, w1.z, w1.w};
    half8 hi, lo;
#pragma unroll
    for (int j = 0; j < 8; ++j) {
        float w = wv[j] * WSCALE;
        _Float16 h = (_Float16)w;
        hi[j] = h;
        lo[j] = (_Float16)(w - (float)h);
    }
    *(half8*)(Wt2 + (size_t)n * (2 * NI) + ic) = hi;
    *(half8*)(Wt2 + (size_t)n * (2 * NI) + NI + ic) = lo;
}

// ---- X f32 -> f16 conversion for a T-range (exact: values are 0/1) ----
__device__ __forceinline__ void xconv_range(const float* __restrict__ x,
                                            _Float16* __restrict__ X16,
                                            int g0, int gstep, int xrows,
                                            int t0, int tc, int T, int NI) {
    int per_row = NI >> 3;
    int G = xrows * per_row;
    for (int g = g0; g < G; g += gstep) {
        int r = g / per_row;
        int gi = g - r * per_row;
        int b = r / tc;
        int tl = r - b * tc;
        size_t off = ((size_t)(b * T + t0 + tl) * NI) + ((size_t)gi << 3);
        const float4* src = (const float4*)(x + off);
        float4 a = src[0], c = src[1];
        half8 o;
        o[0] = (_Float16)a.x; o[1] = (_Float16)a.y;
        o[2] = (_Float16)a.z; o[3] = (_Float16)a.w;
        o[4] = (_Float16)c.x; o[5] = (_Float16)c.y;
        o[6] = (_Float16)c.z; o[7] = (_Float16)c.w;
        *(half8*)(X16 + off) = o;
    }
}

__global__ __launch_bounds__(256) void k_xpre(const float* __restrict__ x,
                                              _Float16* __restrict__ X16,
                                              int xrows, int t0, int tc,
                                              int T, int NI) {
    xconv_range(x, X16, blockIdx.x * 256 + (int)threadIdx.x,
                (int)gridDim.x * 256, xrows, t0, tc, T, NI);
}

// ---- merged chunk kernel (512 threads, NO LDS) ----
// blocks [0, nff)              : 256x256 GEMM tiles of ff chunk c (direct-frag).
// blocks [nff, nff+nrec)       : recurrence over chunk c-1 (4 elems/thread).
// blocks [nff+nrec, end)       : X16 conversion for chunk c+1 (grid-stride).
//  GEMM first so nt = blk % (N/256): XCD x owns nt in {x, x+8} -> its two
//  1 MB B-panels stay L2-resident for the whole chunk.
__global__ __launch_bounds__(512, 2) void k_chunk(
    const _Float16* __restrict__ Wt2, const _Float16* __restrict__ X16,
    _Float16* __restrict__ x16w, const float* __restrict__ xin,
    float* __restrict__ ff_dst, const float* __restrict__ ff_src,
    const float* __restrict__ vin, const float* __restrict__ cin,
    float* __restrict__ vout, float* __restrict__ cout,
    const int* __restrict__ ntype, const float* __restrict__ Evth_p,
    const float* __restrict__ Ivth_p,
    int T, int tc_ff, int t0_ff, int tc_rec, int N, int NI,
    float alpha, float beta, int nff, int nrec, int mv,
    int xrows, int t0_x, int tc_x)
{
    int blk = blockIdx.x;
    int tid = (int)threadIdx.x;
    if (blk < nff) {
        // ---------- ff GEMM tile: C[256 rows][256 cols] over K=2*NI ----------
        int Ntiles = N >> 8;
        int mt = blk / Ntiles;
        int nt = blk - mt * Ntiles;
        int m0 = mt << 8, n0 = nt << 8;
        int wid = tid >> 6, lane = tid & 63;
        int wr = wid >> 2, wc = wid & 3;          // 2 x 4 wave grid
        int ln15 = lane & 15, kh = lane >> 4;

        // Per-lane fragment base pointers. A frag (mh,fi): row = m0 + wr*128
        // + mh*64 + fi*16 + ln15, bytes [kh*16 .. +16). B frag (fj): row =
        // n0 + wc*64 + fj*16 + ln15. Fragment loads are plain 16B global
        // loads; L1 serves the 4x/2x cross-wave reuse, L2 holds the panels.
        const char* aP[8];
#pragma unroll
        for (int mh = 0; mh < 2; ++mh)
#pragma unroll
            for (int fi = 0; fi < 4; ++fi) {
                int r = m0 + wr * 128 + mh * 64 + fi * 16 + ln15;
                if (r > mv - 1) r = mv - 1;              // ragged-M clamp
                int b = r / tc_ff;
                int tl = r - b * tc_ff;
                aP[mh * 4 + fi] =
                    (const char*)(X16 + (size_t)(b * T + t0_ff + tl) * NI) + kh * 16;
            }
        const char* bP[4];
#pragma unroll
        for (int fj = 0; fj < 4; ++fj)
            bP[fj] = (const char*)(Wt2 + (size_t)(n0 + wc * 64 + fj * 16 + ln15) * (2 * NI)) + kh * 16;

        floatx4 acc[8][4] = {};
        int amask = NI - 1;                      // A col wraps over hi/lo passes
        int NKH = (2 * NI) >> 5;                 // 64 k-slices of 32

        for (int kq = 0; kq < NKH; ++kq) {
            int colA = ((kq << 5) & amask) * 2;  // byte offsets
            int colB = (kq << 5) * 2;            // <= 4032, fits imm13
            half8 a[8], b[4];
#pragma unroll
            for (int fj = 0; fj < 4; ++fj) b[fj] = *(const half8*)(bP[fj] + colB);
#pragma unroll
            for (int i = 0; i < 8; ++i) a[i] = *(const half8*)(aP[i] + colA);
#pragma unroll
            for (int mi = 0; mi < 8; ++mi)
#pragma unroll
                for (int fj = 0; fj < 4; ++fj)
                    acc[mi][fj] = __builtin_amdgcn_mfma_f32_16x16x32_f16(
                        a[mi], b[fj], acc[mi][fj], 0, 0, 0);
        }
        // epilogue: C/D layout col=lane&15, row=(lane>>4)*4+e (harness-verified)
#pragma unroll
        for (int ai = 0; ai < 8; ++ai) {
            int r0 = m0 + wr * 128 + (ai >> 2) * 64 + (ai & 3) * 16 + kh * 4;
#pragma unroll
            for (int fj = 0; fj < 4; ++fj) {
                int nn = n0 + wc * 64 + fj * 16 + ln15;
                float* p = ff_dst + (size_t)r0 * N + nn;
#pragma unroll
                for (int e = 0; e < 4; ++e)
                    if (r0 + e < mv) p[(size_t)e * N] = acc[ai][fj][e] * WSCALE_INV;
            }
        }
    } else if (blk < nff + nrec) {
        // ---------- recurrence on previous chunk: 4 consecutive f32/thread --
        int r = (blk - nff) * 512 + tid;          // [0, B*N/4)
        int e0 = r << 2;
        int b = e0 / N;
        int n = e0 - b * N;                       // N%4==0 -> row-local
        float vth[4], v[4], cu[4];
#pragma unroll
        for (int j = 0; j < 4; ++j) vth[j] = (ntype[n + j] == 1) ? Evth_p[0] : Ivth_p[0];
        {
            float4 a0 = *(const float4*)(vin + e0);
            float4 b0 = *(const float4*)(cin + e0);
            v[0]=a0.x; v[1]=a0.y; v[2]=a0.z; v[3]=a0.w;
            cu[0]=b0.x; cu[1]=b0.y; cu[2]=b0.z; cu[3]=b0.w;
        }
        const float* f = ff_src + (size_t)b * tc_rec * N + n;

#define ST1(J, X) \
        cu[J] = __fadd_rn(__fmul_rn(alpha, cu[J]), (X)); \
        v[J]  = __fadd_rn(__fmul_rn(beta, v[J]), cu[J]); \
        v[J]  = (v[J] >= vth[J]) ? 0.0f : v[J];
#define STEP4(A) { ST1(0, (A).x) ST1(1, (A).y) ST1(2, (A).z) ST1(3, (A).w) }

        int t = 0;
        if (tc_rec >= 16) {
            float4 X[8], Y[8];
#pragma unroll
            for (int k = 0; k < 8; ++k) X[k] = *(const float4*)(f + (size_t)k * N);
            for (t = 0; t + 16 <= tc_rec; t += 8) {
#pragma unroll
                for (int k = 0; k < 8; ++k) Y[k] = *(const float4*)(f + (size_t)(t + 8 + k) * N);
#pragma unroll
                for (int k = 0; k < 8; ++k) { STEP4(X[k]) }
#pragma unroll
                for (int k = 0; k < 8; ++k) X[k] = Y[k];
            }
#pragma unroll
            for (int k = 0; k < 8; ++k) { STEP4(X[k]) }
            t += 8;
        }
        for (; t < tc_rec; ++t) {
            float4 a = *(const float4*)(f + (size_t)t * N);
            STEP4(a)
        }
#undef STEP4
#undef ST1
        {
            float4 o0 = {v[0], v[1], v[2], v[3]};
            float4 o1 = {cu[0], cu[1], cu[2], cu[3]};
            *(float4*)(vout + e0) = o0;
            *(float4*)(cout + e0) = o1;
        }
    } else {
        // ---------- X16 conversion for next chunk (rides under GEMM) -------
        int xb = blk - nff - nrec;
        int nxb = (int)gridDim.x - nff - nrec;
        xconv_range(xin, x16w, xb * 512 + tid, nxb * 512,
                    xrows, t0_x, tc_x, T, NI);
    }
}

extern "C" void kernel_launch(void* const* d_in, const int* in_sizes, int n_in,
                              void* d_out, int out_size, void* d_ws, size_t ws_size,
                              hipStream_t stream) {
    const float* initial_v = (const float*)d_in[0];
    const float* initial_I = (const float*)d_in[1];
    const float* inputs    = (const float*)d_in[2];
    // d_in[3] recurrent_weights: dead. d_in[5..6] E/I_weight: dead.
    const float* Wff       = (const float*)d_in[4];
    const float* Evth      = (const float*)d_in[7];
    const float* Ivth      = (const float*)d_in[8];
    const int*   ntype     = (const int*)d_in[9];

    const int N  = in_sizes[9];             // 4096
    const int B  = in_sizes[0] / N;         // 16
    const int NI = in_sizes[4] / N;         // 1024
    const int T  = in_sizes[2] / (B * NI);  // 1000

    char* ws = (char*)d_ws;
    _Float16* Wt2 = (_Float16*)ws;
    size_t wt_b  = (size_t)N * 2 * NI * sizeof(_Float16);
    _Float16* X16 = (_Float16*)(ws + wt_b);
    size_t x_b   = (size_t)B * T * NI * sizeof(_Float16);
    float* state = (float*)(ws + wt_b + x_b);             // [v | cur], 2*B*N
    size_t st_b  = (size_t)2 * B * N * sizeof(float);
    char*  ffbase = ws + wt_b + x_b + st_b;
    size_t fixed  = wt_b + x_b + st_b;

    // ping-pong chunk buffers; TC=208 -> 13 m-tiles -> 208 GEMM blocks,
    // + 32 rec + 16 xconv = 256 = CU count (1 block/CU, no serialization).
    size_t avail = (ws_size > fixed) ? (ws_size - fixed) : 0;
    size_t per_t = (size_t)B * N * sizeof(float);
    int TC = (int)(avail / (2 * per_t));
    if (TC > 208) TC = 208;
    if (TC > T) TC = T;
    TC &= ~15;
    if (TC < 16) TC = 16;

    float* fbuf[2];
    fbuf[0] = (float*)ffbase;
    fbuf[1] = (float*)(ffbase + (size_t)TC * per_t);

    const float alpha = (float)exp(-0.001 / 0.01);   // on current
    const float beta  = (float)exp(-0.001 / 0.005);  // on voltage

    float* st_v = state;
    float* st_c = state + (size_t)B * N;

    // uniform chunk schedule (minimize dispatch count)
    static const int MAXCH = 1024;
    int t0s[MAXCH], tcs[MAXCH];
    int nch = 0;
    {
        int t0 = 0;
        while (t0 < T && nch < MAXCH) {
            int tc = T - t0;
            if (tc > TC) tc = TC;
            t0s[nch] = t0; tcs[nch] = tc;
            t0 += tc; ++nch;
        }
    }

    k_wprep<<<dim3((N * NI / 8 + 255) / 256), 256, 0, stream>>>(Wff, Wt2, N, NI);
    // convert only chunk 0's X slice up front; the rest rides inside k_chunk
    k_xpre<<<dim3(384), 256, 0, stream>>>(inputs, X16, B * tcs[0], 0, tcs[0], T, NI);

    // kernel k: ff(chunk k) [if k<nch] + rec(chunk k-1) [if k>=1]
    //         + xconv(chunk k+1) [if k+1<nch]
    for (int k = 0; k <= nch; ++k) {
        int tc_ff  = (k < nch) ? tcs[k] : 0;
        int t0_ff  = (k < nch) ? t0s[k] : 0;
        int tc_rec = (k >= 1) ? tcs[k - 1] : 0;
        int nrec   = (k >= 1) ? (B * N) / (512 * 4) : 0;   // 32 blocks
        int tc_x   = (k + 1 < nch) ? tcs[k + 1] : 0;
        int t0_x   = (k + 1 < nch) ? t0s[k + 1] : 0;
        int nxb    = (tc_x > 0) ? 16 : 0;
        float* ffd = fbuf[k & 1];
        const float* ffs = fbuf[(k ^ 1) & 1];
        const float* vi = (k == 1) ? initial_v : st_v;
        const float* ci = (k == 1) ? initial_I : st_c;
        float* vo = (k == nch) ? (float*)d_out : st_v;
        float* co = (k == nch) ? ((float*)d_out + (size_t)B * N) : st_c;
        int mv  = B * tc_ff;
        int nff = (tc_ff > 0) ? (((mv + 255) >> 8) * (N >> 8)) : 0;
        int grid = nff + nrec + nxb;
        if (grid == 0) continue;
        k_chunk<<<dim3(grid), 512, 0, stream>>>(Wt2, X16, X16, inputs, ffd, ffs,
                                                vi, ci, vo, co,
                                                ntype, Evth, Ivth,
                                                T, tc_ff, t0_ff, tc_rec, N, NI,
                                                alpha, beta, nff, nrec, mv,
                                                B * tc_x, t0_x, tc_x);
    }
}

// Round 12
// 439.554 us; speedup vs baseline: 2.3693x; 2.3693x over previous
//
#include <hip/hip_runtime.h>
#include <cmath>
#include <cstdint>
#include <cstddef>

// LIF network. Facts exploited:
//  (1) s==0 forever -> recurrent term dead (recurrent_weights, E/I_weight unused).
//  (2) ff = X @ Wff^T is a GEMM; X is exactly 0/1 -> exact in f16. Weights
//      split f16 hi/lo with x1024 scaling (residual <= 2^-22 rel). K = 2048.
//  (3) per T-chunk kernel: ff(chunk c) via MFMA + recurrence(chunk c-1) +
//      xconv(chunk c+1), one segment per block range, grid = 256 = CU count.
//  R11 post-mortem: no-LDS direct fragments = 187us (uncoalesced: 64 lanes x
//      64 different rows per load instr). R8-R11 all lost to the R7 skeleton
//      (72us/tile, 3x reproduced) -> keep the skeleton, CUT ITS WORK:
//      hi-pass and lo-pass share the same A data. Interleave: per 32-col
//      X-block, stage {A, Bhi, Blo} (3 units vs 4) and MFMA A against both
//      B halves. LDS reads 16/iter vs 24 (-33%), A-staging VMEM halved.
//      Same 32 iters, same 8 barriers, same phase bodies. Summation order
//      per element changes (hi/lo interleaved) -> absmax shifts slightly.
//
//  vmcnt LEDGER (per wave; 2 loads per stage-unit; issue order A,Bh,Bl):
//    prologue: STAGE A(0),Bh(0),Bl(0) [6]; VMW2 drains A,Bh(0); BAR.
//    ph0(kt): read bh[s],a0[s]; pre: stage A(kt+1); BAR; MFMA(a0,bh)->acc[0..3]; BAR.
//    ph1(kt): read a1[s]; pre: {stage Bh(kt+1); VMW4 (outstanding Bl(kt)+
//             A,Bh(kt+1)=6 -> drains Bl(kt))} | last: VMW0; BAR;
//             MFMA(a1,bh)->acc[4..7]; BAR.
//    ph2(kt): read bl[s]; pre: stage Bl(kt+1); BAR; MFMA(a0,bl)->acc[0..3]; BAR.
//    ph3(kt): no reads; pre: VMW2 (outstanding A,Bh,Bl(kt+1)=6 -> drains
//             A,Bh(kt+1)); BAR; MFMA(a1,bl)->acc[4..7]; BAR.
//    <=6 loads in flight; never drained to 0 mid-loop. WAR: every stage-write
//    to slot s2 is >=2 barriers after the lgkm-retired last read of s2's old
//    data (reads are consumed by same-phase MFMA pre-BAR2; checked per unit).
//
// ws layout: [ Wt2 (N x 2*NI) f16 | X16 (B*T x NI) f16 |
//              state 2*B*N f32 | ffA | ffB (TC*B*N f32 each) ]

typedef _Float16 half8 __attribute__((ext_vector_type(8)));
typedef float floatx4 __attribute__((ext_vector_type(4)));

#define WSCALE 1024.0f
#define WSCALE_INV (1.0f / 1024.0f)

#define VMW4 asm volatile("s_waitcnt vmcnt(4)" ::: "memory")
#define VMW2 asm volatile("s_waitcnt vmcnt(2)" ::: "memory")
#define VMW0 asm volatile("s_waitcnt vmcnt(0)" ::: "memory")
#define BAR  __builtin_amdgcn_s_barrier()

__device__ __forceinline__ void gload16(const void* g, void* l) {
    __builtin_amdgcn_global_load_lds(
        (const __attribute__((address_space(1))) unsigned int*)g,
        (__attribute__((address_space(3))) unsigned int*)l, 16, 0, 0);
}

// ---- W prep: Wt2[n][k] f16, k<NI: hi(1024*Wff[n][k]); k>=NI: lo residual ----
__global__ __launch_bounds__(256) void k_wprep(const float* __restrict__ Wff,
                                               _Float16* __restrict__ Wt2,
                                               int N, int NI) {
    int tid = blockIdx.x * 256 + (int)threadIdx.x;
    int per_row = NI >> 3;
    int n = tid / per_row;
    int ic = (tid - n * per_row) << 3;
    if (n >= N) return;
    const float4* src = (const float4*)(Wff + (size_t)n * NI + ic);
    float4 w0 = src[0], w1 = src[1];
    float wv[8] = {w0.x, w0.y, w0.z, w0.w, w1.x, w1.y, w1.z, w1.w};
    half8 hi, lo;
#pragma unroll
    for (int j = 0; j < 8; ++j) {
        float w = wv[j] * WSCALE;
        _Float16 h = (_Float16)w;
        hi[j] = h;
        lo[j] = (_Float16)(w - (float)h);
    }
    *(half8*)(Wt2 + (size_t)n * (2 * NI) + ic) = hi;
    *(half8*)(Wt2 + (size_t)n * (2 * NI) + NI + ic) = lo;
}

// ---- X f32 -> f16 conversion for a T-range (exact: values are 0/1) ----
__device__ __forceinline__ void xconv_range(const float* __restrict__ x,
                                            _Float16* __restrict__ X16,
                                            int g0, int gstep, int xrows,
                                            int t0, int tc, int T, int NI) {
    int per_row = NI >> 3;
    int G = xrows * per_row;
    for (int g = g0; g < G; g += gstep) {
        int r = g / per_row;
        int gi = g - r * per_row;
        int b = r / tc;
        int tl = r - b * tc;
        size_t off = ((size_t)(b * T + t0 + tl) * NI) + ((size_t)gi << 3);
        const float4* src = (const float4*)(x + off);
        float4 a = src[0], c = src[1];
        half8 o;
        o[0] = (_Float16)a.x; o[1] = (_Float16)a.y;
        o[2] = (_Float16)a.z; o[3] = (_Float16)a.w;
        o[4] = (_Float16)c.x; o[5] = (_Float16)c.y;
        o[6] = (_Float16)c.z; o[7] = (_Float16)c.w;
        *(half8*)(X16 + off) = o;
    }
}

__global__ __launch_bounds__(256) void k_xpre(const float* __restrict__ x,
                                              _Float16* __restrict__ X16,
                                              int xrows, int t0, int tc,
                                              int T, int NI) {
    xconv_range(x, X16, blockIdx.x * 256 + (int)threadIdx.x,
                (int)gridDim.x * 256, xrows, t0, tc, T, NI);
}

// ---- merged chunk kernel (512 threads) ----
// blocks [0, nff)              : 256x256 GEMM tiles of ff chunk c (4-phase/iter).
// blocks [nff, nff+nrec)       : recurrence over chunk c-1 (4 elems/thread).
// blocks [nff+nrec, end)       : X16 conversion for chunk c+1 (grid-stride).
//  GEMM first so nt = blk % (N/256): XCD x owns nt in {x, x+8} -> its two
//  1 MB B-panels stay L2-resident for the whole chunk.
//  Grid <= 256 so 1 block/CU never serializes.
__global__ __launch_bounds__(512, 2) void k_chunk(
    const _Float16* __restrict__ Wt2, const _Float16* __restrict__ X16,
    _Float16* __restrict__ x16w, const float* __restrict__ xin,
    float* __restrict__ ff_dst, const float* __restrict__ ff_src,
    const float* __restrict__ vin, const float* __restrict__ cin,
    float* __restrict__ vout, float* __restrict__ cout,
    const int* __restrict__ ntype, const float* __restrict__ Evth_p,
    const float* __restrict__ Ivth_p,
    int T, int tc_ff, int t0_ff, int tc_rec, int N, int NI,
    float alpha, float beta, int nff, int nrec, int mv,
    int xrows, int t0_x, int tc_x)
{
    // LDS: [dbuf slot][256 rows][32 k] f16 for A, Bhi, Blo = 96 KiB
    __shared__ _Float16 smA[2][256 * 32];
    __shared__ _Float16 smBh[2][256 * 32];
    __shared__ _Float16 smBl[2][256 * 32];
    int blk = blockIdx.x;
    int tid = (int)threadIdx.x;
    if (blk < nff) {
        // ---------- ff GEMM tile: C[256 rows][256 cols] over K=2*NI ----------
        int Ntiles = N >> 8;
        int mt = blk / Ntiles;
        int nt = blk - mt * Ntiles;
        int m0 = mt << 8, n0 = nt << 8;
        int wid = tid >> 6, lane = tid & 63;
        int wr = wid >> 2, wc = wid & 3;          // 2 x 4 wave grid
        int ln15 = lane & 15, kh = lane >> 4;

        // staging: source slot pre-swizzled by involution slot ^= (row>>1)&3;
        // LDS dest linear (global_load_lds rule); frag read same involution
        // -> conflict-free (verified R3: conflicts 7.9M -> 0).
        int slot4 = (lane & 3) ^ ((lane >> 3) & 3);
        const char* srcA[2]; const char* srcB[2];
        int dB0 = (wid * 2) * 512;               // f16 index of dest block q=0
        int dB1 = dB0 + 512;
#pragma unroll
        for (int q = 0; q < 2; ++q) {
            int rl = (wid * 2 + q) * 16 + (lane >> 2);   // [0,256)
            int rA = m0 + rl;
            if (rA > mv - 1) rA = mv - 1;                // ragged-M clamp
            int b = rA / tc_ff;
            int tl = rA - b * tc_ff;
            srcA[q] = (const char*)(X16 + (size_t)(b * T + t0_ff + tl) * NI + slot4 * 8);
            srcB[q] = (const char*)(Wt2 + (size_t)(n0 + rl) * (2 * NI) + slot4 * 8);
        }
        int NIb = NI * 2;                        // byte offset of lo region

#define STAGE_A(S2, KOFS) { \
        gload16(srcA[0] + (KOFS), &smA[S2][dB0]); \
        gload16(srcA[1] + (KOFS), &smA[S2][dB1]); }
#define STAGE_BH(S2, KOFS) { \
        gload16(srcB[0] + (KOFS), &smBh[S2][dB0]); \
        gload16(srcB[1] + (KOFS), &smBh[S2][dB1]); }
#define STAGE_BL(S2, KOFS) { \
        gload16(srcB[0] + (KOFS), &smBl[S2][dB0]); \
        gload16(srcB[1] + (KOFS), &smBl[S2][dB1]); }

        // prologue: stage block 0 (A, Bhi, Blo); gate A,Bh(0); Bl(0) in flight
        STAGE_A(0, 0);
        STAGE_BH(0, 0);
        STAGE_BL(0, NIb);
        VMW2; BAR;

        // fragment read offsets (same involution, row bits from ln15)
        int sa  = ((kh ^ ((ln15 >> 1) & 3)) << 3);
        int aro = (wr * 128 + ln15) * 32 + sa;   // + mh*2048 + fi*512
        int bro = (wc * 64 + ln15) * 32 + sa;    // + fj*512

        floatx4 acc[8][4] = {};
        int NKT = NI >> 5;                       // 32 X-blocks of 32 cols

        for (int kt = 0; kt < NKT; ++kt) {
            int s = kt & 1, s2 = s ^ 1;
            bool pre = (kt + 1 < NKT);
            int j32b = (kt + 1) << 6;            // next block byte offset
            half8 a0[4], a1[4], bh[4], bl[4];
            // ---- phase 0: read bh,a0; stage A(next); MFMA(a0,bh) -> [0..3]
#pragma unroll
            for (int f = 0; f < 4; ++f) bh[f] = *(const half8*)(&smBh[s][bro + f * 512]);
#pragma unroll
            for (int f = 0; f < 4; ++f) a0[f] = *(const half8*)(&smA[s][aro + f * 512]);
            if (pre) STAGE_A(s2, j32b);
            BAR;
            __builtin_amdgcn_s_setprio(1);
#pragma unroll
            for (int fi = 0; fi < 4; ++fi)
#pragma unroll
                for (int fj = 0; fj < 4; ++fj)
                    acc[fi][fj] = __builtin_amdgcn_mfma_f32_16x16x32_f16(a0[fi], bh[fj], acc[fi][fj], 0, 0, 0);
            __builtin_amdgcn_s_setprio(0);
            BAR;
            // ---- phase 1: read a1; stage Bh(next); gate Bl(kt); MFMA -> [4..7]
#pragma unroll
            for (int f = 0; f < 4; ++f) a1[f] = *(const half8*)(&smA[s][aro + 2048 + f * 512]);
            if (pre) { STAGE_BH(s2, j32b); VMW4; } else { VMW0; }
            BAR;
            __builtin_amdgcn_s_setprio(1);
#pragma unroll
            for (int fi = 0; fi < 4; ++fi)
#pragma unroll
                for (int fj = 0; fj < 4; ++fj)
                    acc[4 + fi][fj] = __builtin_amdgcn_mfma_f32_16x16x32_f16(a1[fi], bh[fj], acc[4 + fi][fj], 0, 0, 0);
            __builtin_amdgcn_s_setprio(0);
            BAR;
            // ---- phase 2: read bl; stage Bl(next); MFMA(a0,bl) -> [0..3]
#pragma unroll
            for (int f = 0; f < 4; ++f) bl[f] = *(const half8*)(&smBl[s][bro + f * 512]);
            if (pre) STAGE_BL(s2, NIb + j32b);
            BAR;
            __builtin_amdgcn_s_setprio(1);
#pragma unroll
            for (int fi = 0; fi < 4; ++fi)
#pragma unroll
                for (int fj = 0; fj < 4; ++fj)
                    acc[fi][fj] = __builtin_amdgcn_mfma_f32_16x16x32_f16(a0[fi], bl[fj], acc[fi][fj], 0, 0, 0);
            __builtin_amdgcn_s_setprio(0);
            BAR;
            // ---- phase 3: no reads; gate A,Bh(kt+1); MFMA(a1,bl) -> [4..7]
            if (pre) { VMW2; }
            BAR;
            __builtin_amdgcn_s_setprio(1);
#pragma unroll
            for (int fi = 0; fi < 4; ++fi)
#pragma unroll
                for (int fj = 0; fj < 4; ++fj)
                    acc[4 + fi][fj] = __builtin_amdgcn_mfma_f32_16x16x32_f16(a1[fi], bl[fj], acc[4 + fi][fj], 0, 0, 0);
            __builtin_amdgcn_s_setprio(0);
            BAR;
        }
#undef STAGE_A
#undef STAGE_BH
#undef STAGE_BL
        // epilogue: C/D layout col=lane&15, row=(lane>>4)*4+e (harness-verified)
#pragma unroll
        for (int ai = 0; ai < 8; ++ai) {
            int r0 = m0 + wr * 128 + (ai >> 2) * 64 + (ai & 3) * 16 + kh * 4;
#pragma unroll
            for (int fj = 0; fj < 4; ++fj) {
                int nn = n0 + wc * 64 + fj * 16 + ln15;
                float* p = ff_dst + (size_t)r0 * N + nn;
#pragma unroll
                for (int e = 0; e < 4; ++e)
                    if (r0 + e < mv) p[(size_t)e * N] = acc[ai][fj][e] * WSCALE_INV;
            }
        }
    } else if (blk < nff + nrec) {
        // ---------- recurrence on previous chunk: 4 consecutive f32/thread --
        int r = (blk - nff) * 512 + tid;          // [0, B*N/4)
        int e0 = r << 2;
        int b = e0 / N;
        int n = e0 - b * N;                       // N%4==0 -> row-local
        float vth[4], v[4], cu[4];
#pragma unroll
        for (int j = 0; j < 4; ++j) vth[j] = (ntype[n + j] == 1) ? Evth_p[0] : Ivth_p[0];
        {
            float4 a0 = *(const float4*)(vin + e0);
            float4 b0 = *(const float4*)(cin + e0);
            v[0]=a0.x; v[1]=a0.y; v[2]=a0.z; v[3]=a0.w;
            cu[0]=b0.x; cu[1]=b0.y; cu[2]=b0.z; cu[3]=b0.w;
        }
        const float* f = ff_src + (size_t)b * tc_rec * N + n;

#define ST1(J, X) \
        cu[J] = __fadd_rn(__fmul_rn(alpha, cu[J]), (X)); \
        v[J]  = __fadd_rn(__fmul_rn(beta, v[J]), cu[J]); \
        v[J]  = (v[J] >= vth[J]) ? 0.0f : v[J];
#define STEP4(A) { ST1(0, (A).x) ST1(1, (A).y) ST1(2, (A).z) ST1(3, (A).w) }

        int t = 0;
        if (tc_rec >= 16) {
            float4 X[8], Y[8];
#pragma unroll
            for (int k = 0; k < 8; ++k) X[k] = *(const float4*)(f + (size_t)k * N);
            for (t = 0; t + 16 <= tc_rec; t += 8) {
#pragma unroll
                for (int k = 0; k < 8; ++k) Y[k] = *(const float4*)(f + (size_t)(t + 8 + k) * N);
#pragma unroll
                for (int k = 0; k < 8; ++k) { STEP4(X[k]) }
#pragma unroll
                for (int k = 0; k < 8; ++k) X[k] = Y[k];
            }
#pragma unroll
            for (int k = 0; k < 8; ++k) { STEP4(X[k]) }
            t += 8;
        }
        for (; t < tc_rec; ++t) {
            float4 a = *(const float4*)(f + (size_t)t * N);
            STEP4(a)
        }
#undef STEP4
#undef ST1
        {
            float4 o0 = {v[0], v[1], v[2], v[3]};
            float4 o1 = {cu[0], cu[1], cu[2], cu[3]};
            *(float4*)(vout + e0) = o0;
            *(float4*)(cout + e0) = o1;
        }
    } else {
        // ---------- X16 conversion for next chunk (rides under GEMM) -------
        int xb = blk - nff - nrec;
        int nxb = (int)gridDim.x - nff - nrec;
        xconv_range(xin, x16w, xb * 512 + tid, nxb * 512,
                    xrows, t0_x, tc_x, T, NI);
    }
}

extern "C" void kernel_launch(void* const* d_in, const int* in_sizes, int n_in,
                              void* d_out, int out_size, void* d_ws, size_t ws_size,
                              hipStream_t stream) {
    const float* initial_v = (const float*)d_in[0];
    const float* initial_I = (const float*)d_in[1];
    const float* inputs    = (const float*)d_in[2];
    // d_in[3] recurrent_weights: dead. d_in[5..6] E/I_weight: dead.
    const float* Wff       = (const float*)d_in[4];
    const float* Evth      = (const float*)d_in[7];
    const float* Ivth      = (const float*)d_in[8];
    const int*   ntype     = (const int*)d_in[9];

    const int N  = in_sizes[9];             // 4096
    const int B  = in_sizes[0] / N;         // 16
    const int NI = in_sizes[4] / N;         // 1024
    const int T  = in_sizes[2] / (B * NI);  // 1000

    char* ws = (char*)d_ws;
    _Float16* Wt2 = (_Float16*)ws;
    size_t wt_b  = (size_t)N * 2 * NI * sizeof(_Float16);
    _Float16* X16 = (_Float16*)(ws + wt_b);
    size_t x_b   = (size_t)B * T * NI * sizeof(_Float16);
    float* state = (float*)(ws + wt_b + x_b);             // [v | cur], 2*B*N
    size_t st_b  = (size_t)2 * B * N * sizeof(float);
    char*  ffbase = ws + wt_b + x_b + st_b;
    size_t fixed  = wt_b + x_b + st_b;

    // ping-pong chunk buffers; TC=208 -> 13 m-tiles -> 208 GEMM blocks,
    // + 32 rec + 16 xconv = 256 = CU count (1 block/CU, no serialization).
    size_t avail = (ws_size > fixed) ? (ws_size - fixed) : 0;
    size_t per_t = (size_t)B * N * sizeof(float);
    int TC = (int)(avail / (2 * per_t));
    if (TC > 208) TC = 208;
    if (TC > T) TC = T;
    TC &= ~15;
    if (TC < 16) TC = 16;

    float* fbuf[2];
    fbuf[0] = (float*)ffbase;
    fbuf[1] = (float*)(ffbase + (size_t)TC * per_t);

    const float alpha = (float)exp(-0.001 / 0.01);   // on current
    const float beta  = (float)exp(-0.001 / 0.005);  // on voltage

    float* st_v = state;
    float* st_c = state + (size_t)B * N;

    // uniform chunk schedule (minimize dispatch count)
    static const int MAXCH = 1024;
    int t0s[MAXCH], tcs[MAXCH];
    int nch = 0;
    {
        int t0 = 0;
        while (t0 < T && nch < MAXCH) {
            int tc = T - t0;
            if (tc > TC) tc = TC;
            t0s[nch] = t0; tcs[nch] = tc;
            t0 += tc; ++nch;
        }
    }

    k_wprep<<<dim3((N * NI / 8 + 255) / 256), 256, 0, stream>>>(Wff, Wt2, N, NI);
    // convert only chunk 0's X slice up front; the rest rides inside k_chunk
    k_xpre<<<dim3(384), 256, 0, stream>>>(inputs, X16, B * tcs[0], 0, tcs[0], T, NI);

    // kernel k: ff(chunk k) [if k<nch] + rec(chunk k-1) [if k>=1]
    //         + xconv(chunk k+1) [if k+1<nch]
    for (int k = 0; k <= nch; ++k) {
        int tc_ff  = (k < nch) ? tcs[k] : 0;
        int t0_ff  = (k < nch) ? t0s[k] : 0;
        int tc_rec = (k >= 1) ? tcs[k - 1] : 0;
        int nrec   = (k >= 1) ? (B * N) / (512 * 4) : 0;   // 32 blocks
        int tc_x   = (k + 1 < nch) ? tcs[k + 1] : 0;
        int t0_x   = (k + 1 < nch) ? t0s[k + 1] : 0;
        int nxb    = (tc_x > 0) ? 16 : 0;
        float* ffd = fbuf[k & 1];
        const float* ffs = fbuf[(k ^ 1) & 1];
        const float* vi = (k == 1) ? initial_v : st_v;
        const float* ci = (k == 1) ? initial_I : st_c;
        float* vo = (k == nch) ? (float*)d_out : st_v;
        float* co = (k == nch) ? ((float*)d_out + (size_t)B * N) : st_c;
        int mv  = B * tc_ff;
        int nff = (tc_ff > 0) ? (((mv + 255) >> 8) * (N >> 8)) : 0;
        int grid = nff + nrec + nxb;
        if (grid == 0) continue;
        k_chunk<<<dim3(grid), 512, 0, stream>>>(Wt2, X16, X16, inputs, ffd, ffs,
                                                vi, ci, vo, co,
                                                ntype, Evth, Ivth,
                                                T, tc_ff, t0_ff, tc_rec, N, NI,
                                                alpha, beta, nff, nrec, mv,
                                                B * tc_x, t0_x, tc_x);
    }
}

// Round 13
// 436.659 us; speedup vs baseline: 2.3850x; 1.0066x over previous
//
#include <hip/hip_runtime.h>
#include <cmath>
#include <cstdint>
#include <cstddef>

// LIF network. Facts exploited:
//  (1) s==0 forever -> recurrent term dead (recurrent_weights, E/I_weight unused).
//  (2) ff = X @ Wff^T is a GEMM; X is exactly 0/1 -> exact in f16. Weights
//      split f16 hi/lo with x1024 scaling (residual <= 2^-22 rel). K = 2048.
//  (3) per T-chunk kernel: ff(chunk c) via MFMA + recurrence(chunk c-1) +
//      xconv(chunk c+1), one segment per block range, grid = 256 = CU count.
//  R12 post-mortem: hi/lo-shared-A interleave WORKED (best total 439.6us,
//      FETCH halved, absmax improved to 0.0039 via pairwise hi/lo adds).
//      Cycle audit: 5957 cyc/iter vs ~2000 pipe floor; excess scales with the
//      8 barrier-pairs/iter, and ph3 contains ZERO ds_reads (operands read in
//      ph1/ph2). This version: merge ph3's MFMA cluster into ph2 -> 3 phases,
//      6 barriers/iter. Reads, staging, and per-acc MFMA order unchanged ->
//      output bitwise identical to R12 (absmax must be exactly 0.00390625).
//
//  vmcnt LEDGER (per wave; 2 loads per stage-unit; issue order A,Bh,Bl):
//    prologue: STAGE A(0),Bh(0),Bl(0) [6]; VMW2 drains A,Bh(0); BAR.
//    ph0(kt): read bh[s],a0[s]; pre: stage A(kt+1); BAR;
//             MFMA(a0,bh)->acc[0..3]; BAR.
//    ph1(kt): read a1[s]; pre: {stage Bh(kt+1); VMW4 (outstanding Bl(kt)+
//             A,Bh(kt+1)=6 -> drains Bl(kt))} | last: VMW0; BAR;
//             MFMA(a1,bh)->acc[4..7]; BAR.
//    ph2(kt): read bl[s]; pre: {stage Bl(kt+1); VMW2 (outstanding
//             A,Bh,Bl(kt+1)=6 -> drains A,Bh(kt+1), leaves Bl(kt+1))}; BAR;
//             MFMA(a0,bl)->acc[0..3]; MFMA(a1,bl)->acc[4..7]; BAR.
//    <=6 loads in flight; never drained to 0 mid-loop. WAR: every stage-write
//    to slot s2 is >=2 barriers after the lgkm-retired last read of s2's old
//    data (reads consumed by same/next-phase MFMA pre-BAR2; checked per unit).
//
// ws layout: [ Wt2 (N x 2*NI) f16 | X16 (B*T x NI) f16 |
//              state 2*B*N f32 | ffA | ffB (TC*B*N f32 each) ]

typedef _Float16 half8 __attribute__((ext_vector_type(8)));
typedef float floatx4 __attribute__((ext_vector_type(4)));

#define WSCALE 1024.0f
#define WSCALE_INV (1.0f / 1024.0f)

#define VMW4 asm volatile("s_waitcnt vmcnt(4)" ::: "memory")
#define VMW2 asm volatile("s_waitcnt vmcnt(2)" ::: "memory")
#define VMW0 asm volatile("s_waitcnt vmcnt(0)" ::: "memory")
#define BAR  __builtin_amdgcn_s_barrier()

__device__ __forceinline__ void gload16(const void* g, void* l) {
    __builtin_amdgcn_global_load_lds(
        (const __attribute__((address_space(1))) unsigned int*)g,
        (__attribute__((address_space(3))) unsigned int*)l, 16, 0, 0);
}

// ---- W prep: Wt2[n][k] f16, k<NI: hi(1024*Wff[n][k]); k>=NI: lo residual ----
__global__ __launch_bounds__(256) void k_wprep(const float* __restrict__ Wff,
                                               _Float16* __restrict__ Wt2,
                                               int N, int NI) {
    int tid = blockIdx.x * 256 + (int)threadIdx.x;
    int per_row = NI >> 3;
    int n = tid / per_row;
    int ic = (tid - n * per_row) << 3;
    if (n >= N) return;
    const float4* src = (const float4*)(Wff + (size_t)n * NI + ic);
    float4 w0 = src[0], w1 = src[1];
    float wv[8] = {w0.x, w0.y, w0.z, w0.w, w1.x, w1.y, w1.z, w1.w};
    half8 hi, lo;
#pragma unroll
    for (int j = 0; j < 8; ++j) {
        float w = wv[j] * WSCALE;
        _Float16 h = (_Float16)w;
        hi[j] = h;
        lo[j] = (_Float16)(w - (float)h);
    }
    *(half8*)(Wt2 + (size_t)n * (2 * NI) + ic) = hi;
    *(half8*)(Wt2 + (size_t)n * (2 * NI) + NI + ic) = lo;
}

// ---- X f32 -> f16 conversion for a T-range (exact: values are 0/1) ----
__device__ __forceinline__ void xconv_range(const float* __restrict__ x,
                                            _Float16* __restrict__ X16,
                                            int g0, int gstep, int xrows,
                                            int t0, int tc, int T, int NI) {
    int per_row = NI >> 3;
    int G = xrows * per_row;
    for (int g = g0; g < G; g += gstep) {
        int r = g / per_row;
        int gi = g - r * per_row;
        int b = r / tc;
        int tl = r - b * tc;
        size_t off = ((size_t)(b * T + t0 + tl) * NI) + ((size_t)gi << 3);
        const float4* src = (const float4*)(x + off);
        float4 a = src[0], c = src[1];
        half8 o;
        o[0] = (_Float16)a.x; o[1] = (_Float16)a.y;
        o[2] = (_Float16)a.z; o[3] = (_Float16)a.w;
        o[4] = (_Float16)c.x; o[5] = (_Float16)c.y;
        o[6] = (_Float16)c.z; o[7] = (_Float16)c.w;
        *(half8*)(X16 + off) = o;
    }
}

__global__ __launch_bounds__(256) void k_xpre(const float* __restrict__ x,
                                              _Float16* __restrict__ X16,
                                              int xrows, int t0, int tc,
                                              int T, int NI) {
    xconv_range(x, X16, blockIdx.x * 256 + (int)threadIdx.x,
                (int)gridDim.x * 256, xrows, t0, tc, T, NI);
}

// ---- merged chunk kernel (512 threads) ----
// blocks [0, nff)              : 256x256 GEMM tiles of ff chunk c (3-phase/iter).
// blocks [nff, nff+nrec)       : recurrence over chunk c-1 (4 elems/thread).
// blocks [nff+nrec, end)       : X16 conversion for chunk c+1 (grid-stride).
//  GEMM first so nt = blk % (N/256): XCD x owns nt in {x, x+8} -> its two
//  1 MB B-panels stay L2-resident for the whole chunk.
//  Grid <= 256 so 1 block/CU never serializes.
__global__ __launch_bounds__(512, 2) void k_chunk(
    const _Float16* __restrict__ Wt2, const _Float16* __restrict__ X16,
    _Float16* __restrict__ x16w, const float* __restrict__ xin,
    float* __restrict__ ff_dst, const float* __restrict__ ff_src,
    const float* __restrict__ vin, const float* __restrict__ cin,
    float* __restrict__ vout, float* __restrict__ cout,
    const int* __restrict__ ntype, const float* __restrict__ Evth_p,
    const float* __restrict__ Ivth_p,
    int T, int tc_ff, int t0_ff, int tc_rec, int N, int NI,
    float alpha, float beta, int nff, int nrec, int mv,
    int xrows, int t0_x, int tc_x)
{
    // LDS: [dbuf slot][256 rows][32 k] f16 for A, Bhi, Blo = 96 KiB
    __shared__ _Float16 smA[2][256 * 32];
    __shared__ _Float16 smBh[2][256 * 32];
    __shared__ _Float16 smBl[2][256 * 32];
    int blk = blockIdx.x;
    int tid = (int)threadIdx.x;
    if (blk < nff) {
        // ---------- ff GEMM tile: C[256 rows][256 cols] over K=2*NI ----------
        int Ntiles = N >> 8;
        int mt = blk / Ntiles;
        int nt = blk - mt * Ntiles;
        int m0 = mt << 8, n0 = nt << 8;
        int wid = tid >> 6, lane = tid & 63;
        int wr = wid >> 2, wc = wid & 3;          // 2 x 4 wave grid
        int ln15 = lane & 15, kh = lane >> 4;

        // staging: source slot pre-swizzled by involution slot ^= (row>>1)&3;
        // LDS dest linear (global_load_lds rule); frag read same involution
        // -> conflict-free (verified R3: conflicts 7.9M -> 0).
        int slot4 = (lane & 3) ^ ((lane >> 3) & 3);
        const char* srcA[2]; const char* srcB[2];
        int dB0 = (wid * 2) * 512;               // f16 index of dest block q=0
        int dB1 = dB0 + 512;
#pragma unroll
        for (int q = 0; q < 2; ++q) {
            int rl = (wid * 2 + q) * 16 + (lane >> 2);   // [0,256)
            int rA = m0 + rl;
            if (rA > mv - 1) rA = mv - 1;                // ragged-M clamp
            int b = rA / tc_ff;
            int tl = rA - b * tc_ff;
            srcA[q] = (const char*)(X16 + (size_t)(b * T + t0_ff + tl) * NI + slot4 * 8);
            srcB[q] = (const char*)(Wt2 + (size_t)(n0 + rl) * (2 * NI) + slot4 * 8);
        }
        int NIb = NI * 2;                        // byte offset of lo region

#define STAGE_A(S2, KOFS) { \
        gload16(srcA[0] + (KOFS), &smA[S2][dB0]); \
        gload16(srcA[1] + (KOFS), &smA[S2][dB1]); }
#define STAGE_BH(S2, KOFS) { \
        gload16(srcB[0] + (KOFS), &smBh[S2][dB0]); \
        gload16(srcB[1] + (KOFS), &smBh[S2][dB1]); }
#define STAGE_BL(S2, KOFS) { \
        gload16(srcB[0] + (KOFS), &smBl[S2][dB0]); \
        gload16(srcB[1] + (KOFS), &smBl[S2][dB1]); }

        // prologue: stage block 0 (A, Bhi, Blo); gate A,Bh(0); Bl(0) in flight
        STAGE_A(0, 0);
        STAGE_BH(0, 0);
        STAGE_BL(0, NIb);
        VMW2; BAR;

        // fragment read offsets (same involution, row bits from ln15)
        int sa  = ((kh ^ ((ln15 >> 1) & 3)) << 3);
        int aro = (wr * 128 + ln15) * 32 + sa;   // + mh*2048 + fi*512
        int bro = (wc * 64 + ln15) * 32 + sa;    // + fj*512

        floatx4 acc[8][4] = {};
        int NKT = NI >> 5;                       // 32 X-blocks of 32 cols

        for (int kt = 0; kt < NKT; ++kt) {
            int s = kt & 1, s2 = s ^ 1;
            bool pre = (kt + 1 < NKT);
            int j32b = (kt + 1) << 6;            // next block byte offset
            half8 a0[4], a1[4], bh[4], bl[4];
            // ---- phase 0: read bh,a0; stage A(next); MFMA(a0,bh) -> [0..3]
#pragma unroll
            for (int f = 0; f < 4; ++f) bh[f] = *(const half8*)(&smBh[s][bro + f * 512]);
#pragma unroll
            for (int f = 0; f < 4; ++f) a0[f] = *(const half8*)(&smA[s][aro + f * 512]);
            if (pre) STAGE_A(s2, j32b);
            BAR;
            __builtin_amdgcn_s_setprio(1);
#pragma unroll
            for (int fi = 0; fi < 4; ++fi)
#pragma unroll
                for (int fj = 0; fj < 4; ++fj)
                    acc[fi][fj] = __builtin_amdgcn_mfma_f32_16x16x32_f16(a0[fi], bh[fj], acc[fi][fj], 0, 0, 0);
            __builtin_amdgcn_s_setprio(0);
            BAR;
            // ---- phase 1: read a1; stage Bh(next); gate Bl(kt); MFMA -> [4..7]
#pragma unroll
            for (int f = 0; f < 4; ++f) a1[f] = *(const half8*)(&smA[s][aro + 2048 + f * 512]);
            if (pre) { STAGE_BH(s2, j32b); VMW4; } else { VMW0; }
            BAR;
            __builtin_amdgcn_s_setprio(1);
#pragma unroll
            for (int fi = 0; fi < 4; ++fi)
#pragma unroll
                for (int fj = 0; fj < 4; ++fj)
                    acc[4 + fi][fj] = __builtin_amdgcn_mfma_f32_16x16x32_f16(a1[fi], bh[fj], acc[4 + fi][fj], 0, 0, 0);
            __builtin_amdgcn_s_setprio(0);
            BAR;
            // ---- phase 2 (merged old ph2+ph3): read bl; stage Bl(next);
            //      gate A,Bh(kt+1); MFMA(a0,bl)->[0..3]; MFMA(a1,bl)->[4..7]
#pragma unroll
            for (int f = 0; f < 4; ++f) bl[f] = *(const half8*)(&smBl[s][bro + f * 512]);
            if (pre) { STAGE_BL(s2, NIb + j32b); VMW2; }
            BAR;
            __builtin_amdgcn_s_setprio(1);
#pragma unroll
            for (int fi = 0; fi < 4; ++fi)
#pragma unroll
                for (int fj = 0; fj < 4; ++fj)
                    acc[fi][fj] = __builtin_amdgcn_mfma_f32_16x16x32_f16(a0[fi], bl[fj], acc[fi][fj], 0, 0, 0);
#pragma unroll
            for (int fi = 0; fi < 4; ++fi)
#pragma unroll
                for (int fj = 0; fj < 4; ++fj)
                    acc[4 + fi][fj] = __builtin_amdgcn_mfma_f32_16x16x32_f16(a1[fi], bl[fj], acc[4 + fi][fj], 0, 0, 0);
            __builtin_amdgcn_s_setprio(0);
            BAR;
        }
#undef STAGE_A
#undef STAGE_BH
#undef STAGE_BL
        // epilogue: C/D layout col=lane&15, row=(lane>>4)*4+e (harness-verified)
#pragma unroll
        for (int ai = 0; ai < 8; ++ai) {
            int r0 = m0 + wr * 128 + (ai >> 2) * 64 + (ai & 3) * 16 + kh * 4;
#pragma unroll
            for (int fj = 0; fj < 4; ++fj) {
                int nn = n0 + wc * 64 + fj * 16 + ln15;
                float* p = ff_dst + (size_t)r0 * N + nn;
#pragma unroll
                for (int e = 0; e < 4; ++e)
                    if (r0 + e < mv) p[(size_t)e * N] = acc[ai][fj][e] * WSCALE_INV;
            }
        }
    } else if (blk < nff + nrec) {
        // ---------- recurrence on previous chunk: 4 consecutive f32/thread --
        int r = (blk - nff) * 512 + tid;          // [0, B*N/4)
        int e0 = r << 2;
        int b = e0 / N;
        int n = e0 - b * N;                       // N%4==0 -> row-local
        float vth[4], v[4], cu[4];
#pragma unroll
        for (int j = 0; j < 4; ++j) vth[j] = (ntype[n + j] == 1) ? Evth_p[0] : Ivth_p[0];
        {
            float4 a0 = *(const float4*)(vin + e0);
            float4 b0 = *(const float4*)(cin + e0);
            v[0]=a0.x; v[1]=a0.y; v[2]=a0.z; v[3]=a0.w;
            cu[0]=b0.x; cu[1]=b0.y; cu[2]=b0.z; cu[3]=b0.w;
        }
        const float* f = ff_src + (size_t)b * tc_rec * N + n;

#define ST1(J, X) \
        cu[J] = __fadd_rn(__fmul_rn(alpha, cu[J]), (X)); \
        v[J]  = __fadd_rn(__fmul_rn(beta, v[J]), cu[J]); \
        v[J]  = (v[J] >= vth[J]) ? 0.0f : v[J];
#define STEP4(A) { ST1(0, (A).x) ST1(1, (A).y) ST1(2, (A).z) ST1(3, (A).w) }

        int t = 0;
        if (tc_rec >= 16) {
            float4 X[8], Y[8];
#pragma unroll
            for (int k = 0; k < 8; ++k) X[k] = *(const float4*)(f + (size_t)k * N);
            for (t = 0; t + 16 <= tc_rec; t += 8) {
#pragma unroll
                for (int k = 0; k < 8; ++k) Y[k] = *(const float4*)(f + (size_t)(t + 8 + k) * N);
#pragma unroll
                for (int k = 0; k < 8; ++k) { STEP4(X[k]) }
#pragma unroll
                for (int k = 0; k < 8; ++k) X[k] = Y[k];
            }
#pragma unroll
            for (int k = 0; k < 8; ++k) { STEP4(X[k]) }
            t += 8;
        }
        for (; t < tc_rec; ++t) {
            float4 a = *(const float4*)(f + (size_t)t * N);
            STEP4(a)
        }
#undef STEP4
#undef ST1
        {
            float4 o0 = {v[0], v[1], v[2], v[3]};
            float4 o1 = {cu[0], cu[1], cu[2], cu[3]};
            *(float4*)(vout + e0) = o0;
            *(float4*)(cout + e0) = o1;
        }
    } else {
        // ---------- X16 conversion for next chunk (rides under GEMM) -------
        int xb = blk - nff - nrec;
        int nxb = (int)gridDim.x - nff - nrec;
        xconv_range(xin, x16w, xb * 512 + tid, nxb * 512,
                    xrows, t0_x, tc_x, T, NI);
    }
}

extern "C" void kernel_launch(void* const* d_in, const int* in_sizes, int n_in,
                              void* d_out, int out_size, void* d_ws, size_t ws_size,
                              hipStream_t stream) {
    const float* initial_v = (const float*)d_in[0];
    const float* initial_I = (const float*)d_in[1];
    const float* inputs    = (const float*)d_in[2];
    // d_in[3] recurrent_weights: dead. d_in[5..6] E/I_weight: dead.
    const float* Wff       = (const float*)d_in[4];
    const float* Evth      = (const float*)d_in[7];
    const float* Ivth      = (const float*)d_in[8];
    const int*   ntype     = (const int*)d_in[9];

    const int N  = in_sizes[9];             // 4096
    const int B  = in_sizes[0] / N;         // 16
    const int NI = in_sizes[4] / N;         // 1024
    const int T  = in_sizes[2] / (B * NI);  // 1000

    char* ws = (char*)d_ws;
    _Float16* Wt2 = (_Float16*)ws;
    size_t wt_b  = (size_t)N * 2 * NI * sizeof(_Float16);
    _Float16* X16 = (_Float16*)(ws + wt_b);
    size_t x_b   = (size_t)B * T * NI * sizeof(_Float16);
    float* state = (float*)(ws + wt_b + x_b);             // [v | cur], 2*B*N
    size_t st_b  = (size_t)2 * B * N * sizeof(float);
    char*  ffbase = ws + wt_b + x_b + st_b;
    size_t fixed  = wt_b + x_b + st_b;

    // ping-pong chunk buffers; TC=208 -> 13 m-tiles -> 208 GEMM blocks,
    // + 32 rec + 16 xconv = 256 = CU count (1 block/CU, no serialization).
    size_t avail = (ws_size > fixed) ? (ws_size - fixed) : 0;
    size_t per_t = (size_t)B * N * sizeof(float);
    int TC = (int)(avail / (2 * per_t));
    if (TC > 208) TC = 208;
    if (TC > T) TC = T;
    TC &= ~15;
    if (TC < 16) TC = 16;

    float* fbuf[2];
    fbuf[0] = (float*)ffbase;
    fbuf[1] = (float*)(ffbase + (size_t)TC * per_t);

    const float alpha = (float)exp(-0.001 / 0.01);   // on current
    const float beta  = (float)exp(-0.001 / 0.005);  // on voltage

    float* st_v = state;
    float* st_c = state + (size_t)B * N;

    // uniform chunk schedule (minimize dispatch count)
    static const int MAXCH = 1024;
    int t0s[MAXCH], tcs[MAXCH];
    int nch = 0;
    {
        int t0 = 0;
        while (t0 < T && nch < MAXCH) {
            int tc = T - t0;
            if (tc > TC) tc = TC;
            t0s[nch] = t0; tcs[nch] = tc;
            t0 += tc; ++nch;
        }
    }

    k_wprep<<<dim3((N * NI / 8 + 255) / 256), 256, 0, stream>>>(Wff, Wt2, N, NI);
    // convert only chunk 0's X slice up front; the rest rides inside k_chunk
    k_xpre<<<dim3(384), 256, 0, stream>>>(inputs, X16, B * tcs[0], 0, tcs[0], T, NI);

    // kernel k: ff(chunk k) [if k<nch] + rec(chunk k-1) [if k>=1]
    //         + xconv(chunk k+1) [if k+1<nch]
    for (int k = 0; k <= nch; ++k) {
        int tc_ff  = (k < nch) ? tcs[k] : 0;
        int t0_ff  = (k < nch) ? t0s[k] : 0;
        int tc_rec = (k >= 1) ? tcs[k - 1] : 0;
        int nrec   = (k >= 1) ? (B * N) / (512 * 4) : 0;   // 32 blocks
        int tc_x   = (k + 1 < nch) ? tcs[k + 1] : 0;
        int t0_x   = (k + 1 < nch) ? t0s[k + 1] : 0;
        int nxb    = (tc_x > 0) ? 16 : 0;
        float* ffd = fbuf[k & 1];
        const float* ffs = fbuf[(k ^ 1) & 1];
        const float* vi = (k == 1) ? initial_v : st_v;
        const float* ci = (k == 1) ? initial_I : st_c;
        float* vo = (k == nch) ? (float*)d_out : st_v;
        float* co = (k == nch) ? ((float*)d_out + (size_t)B * N) : st_c;
        int mv  = B * tc_ff;
        int nff = (tc_ff > 0) ? (((mv + 255) >> 8) * (N >> 8)) : 0;
        int grid = nff + nrec + nxb;
        if (grid == 0) continue;
        k_chunk<<<dim3(grid), 512, 0, stream>>>(Wt2, X16, X16, inputs, ffd, ffs,
                                                vi, ci, vo, co,
                                                ntype, Evth, Ivth,
                                                T, tc_ff, t0_ff, tc_rec, N, NI,
                                                alpha, beta, nff, nrec, mv,
                                                B * tc_x, t0_x, tc_x);
    }
}